// Round 3
// baseline (78.117 us; speedup 1.0000x reference)
//
#include <hip/hip_runtime.h>

// QuantumLayer: 4-qubit, 4-layer VQC over batch B.
// R2: M values stored SPLATTED ({v,v} pairs) so uniform loads land in SGPR
// pairs usable directly as v_pk_fma_f32 operands (no per-gate splat movs).
// __launch_bounds__(256,4) caps VGPRs at 128 for 4 waves/SIMD.
// State indexing: flat k = w0*8 + w1*4 + w2*2 + w3  (wire i -> bit (3-i)).

typedef float v2f __attribute__((ext_vector_type(2)));

// ---- Precompute M = RZ(pz)*RY(py) per (layer, wire). SU(2): alpha=M00,
// beta=M01; each of {ar,ai,br,bi} written twice (splatted) at
// ws[(l*4+w)*8 + 2*j .. +1]. ----
__global__ void qlayer_precompute(const float* __restrict__ w, float* __restrict__ M) {
  int t = blockIdx.x * blockDim.x + threadIdx.x;
  if (t < 16) {
    int l = t >> 2, q = t & 3;
    float ay = 0.5f * w[8 * l + q];       // RY angle /2
    float az = 0.5f * w[8 * l + 4 + q];   // RZ angle /2
    float cy = cosf(ay), sy = sinf(ay);
    float cz = cosf(az), sz = sinf(az);
    float* m = M + t * 8;
    float ar = cz * cy, ai = -sz * cy, br = -cz * sy, bi = sz * sy;
    m[0] = ar; m[1] = ar;
    m[2] = ai; m[3] = ai;
    m[4] = br; m[5] = br;
    m[6] = bi; m[7] = bi;
  }
}

// G = M * RX(cx, sx) is SU(2): G = [[g, d], [-conj(d), conj(g)]].
// M2 entries are uniform v2f (splatted) -> SGPR pairs feeding VOP3P directly.
__device__ __forceinline__ void make_g2(const v2f* __restrict__ M2, int idx,
                                        v2f cx, v2f sxv,
                                        v2f& gr, v2f& gi, v2f& dr, v2f& di) {
  v2f ar = M2[idx * 4 + 0], ai = M2[idx * 4 + 1];
  v2f br = M2[idx * 4 + 2], bi = M2[idx * 4 + 3];
  gr = ar * cx + bi * sxv;
  gi = ai * cx - br * sxv;
  dr = ai * sxv + br * cx;
  di = bi * cx - ar * sxv;
}

// Apply SU(2) gate [[g,d],[-conj(d),conj(g)]] on wire W (bit 3-W).
template <int W>
__device__ __forceinline__ void apply_su2(v2f (&sr)[16], v2f (&si)[16],
                                          v2f gr, v2f gi, v2f dr, v2f di) {
  constexpr int stride = 8 >> W;
#pragma unroll
  for (int base = 0; base < 16; base += 2 * stride) {
#pragma unroll
    for (int j = 0; j < stride; ++j) {
      const int k0 = base + j, k1 = k0 + stride;
      v2f a0r = sr[k0], a0i = si[k0], a1r = sr[k1], a1i = si[k1];
      sr[k0] = gr * a0r - gi * a0i + dr * a1r - di * a1i;
      si[k0] = gr * a0i + gi * a0r + dr * a1i + di * a1r;
      sr[k1] = gr * a1r + gi * a1i - dr * a0r - di * a0i;
      si[k1] = gr * a1i - gi * a1r - dr * a0i + di * a0r;
    }
  }
}

// CNOT(control C, target T): pure register permutation (fully unrolled).
template <int C, int T>
__device__ __forceinline__ void apply_cnot_(v2f (&sr)[16], v2f (&si)[16]) {
  constexpr int cb = 8 >> C, tb = 8 >> T;
#pragma unroll
  for (int k = 0; k < 16; ++k) {
    if ((k & cb) && !(k & tb)) {
      const int k2 = k | tb;
      v2f tr = sr[k]; sr[k] = sr[k2]; sr[k2] = tr;
      v2f ti = si[k]; si[k] = si[k2]; si[k2] = ti;
    }
  }
}

__global__ __launch_bounds__(256, 4) void qlayer_main(const float* __restrict__ x,
                                                      const v2f* __restrict__ M2,
                                                      float* __restrict__ out) {
  int t = blockIdx.x * blockDim.x + threadIdx.x;  // owns batch elems 2t, 2t+1

  float4 xv0 = reinterpret_cast<const float4*>(x)[2 * t];
  float4 xv1 = reinterpret_cast<const float4*>(x)[2 * t + 1];
  v2f cx[4], sx[4];
  {
    float c, s;
    __sincosf(0.5f * xv0.x, &s, &c); sx[0].x = s; cx[0].x = c;
    __sincosf(0.5f * xv0.y, &s, &c); sx[1].x = s; cx[1].x = c;
    __sincosf(0.5f * xv0.z, &s, &c); sx[2].x = s; cx[2].x = c;
    __sincosf(0.5f * xv0.w, &s, &c); sx[3].x = s; cx[3].x = c;
    __sincosf(0.5f * xv1.x, &s, &c); sx[0].y = s; cx[0].y = c;
    __sincosf(0.5f * xv1.y, &s, &c); sx[1].y = s; cx[1].y = c;
    __sincosf(0.5f * xv1.z, &s, &c); sx[2].y = s; cx[2].y = c;
    __sincosf(0.5f * xv1.w, &s, &c); sx[3].y = s; cx[3].y = c;
  }

  v2f sr[16], si[16];

  // ---- Layer 0 on |0000>: product state of G_w column 0 = (g, -conj(d)) ----
  {
    v2f c0r[4][2], c0i[4][2];
#pragma unroll
    for (int w = 0; w < 4; ++w) {
      v2f gr, gi, dr, di;
      make_g2(M2, w, cx[w], sx[w], gr, gi, dr, di);
      c0r[w][0] = gr;  c0i[w][0] = gi;   // bit = 0
      c0r[w][1] = -dr; c0i[w][1] = di;   // bit = 1
    }
    v2f t4r[4], t4i[4];
#pragma unroll
    for (int a = 0; a < 2; ++a)
#pragma unroll
      for (int b1 = 0; b1 < 2; ++b1) {
        t4r[a * 2 + b1] = c0r[0][a] * c0r[1][b1] - c0i[0][a] * c0i[1][b1];
        t4i[a * 2 + b1] = c0r[0][a] * c0i[1][b1] + c0i[0][a] * c0r[1][b1];
      }
    v2f t8r[8], t8i[8];
#pragma unroll
    for (int a = 0; a < 4; ++a)
#pragma unroll
      for (int b2 = 0; b2 < 2; ++b2) {
        t8r[a * 2 + b2] = t4r[a] * c0r[2][b2] - t4i[a] * c0i[2][b2];
        t8i[a * 2 + b2] = t4r[a] * c0i[2][b2] + t4i[a] * c0r[2][b2];
      }
#pragma unroll
    for (int a = 0; a < 8; ++a)
#pragma unroll
      for (int b3 = 0; b3 < 2; ++b3) {
        sr[a * 2 + b3] = t8r[a] * c0r[3][b3] - t8i[a] * c0i[3][b3];
        si[a * 2 + b3] = t8r[a] * c0i[3][b3] + t8i[a] * c0r[3][b3];
      }
  }
  apply_cnot_<2, 3>(sr, si);
  apply_cnot_<1, 2>(sr, si);
  apply_cnot_<0, 1>(sr, si);
  apply_cnot_<3, 0>(sr, si);

  // ---- Layers 1..3 ----
#pragma unroll
  for (int l = 1; l < 4; ++l) {
    v2f gr, gi, dr, di;
    make_g2(M2, l * 4 + 0, cx[0], sx[0], gr, gi, dr, di);
    apply_su2<0>(sr, si, gr, gi, dr, di);
    make_g2(M2, l * 4 + 1, cx[1], sx[1], gr, gi, dr, di);
    apply_su2<1>(sr, si, gr, gi, dr, di);
    make_g2(M2, l * 4 + 2, cx[2], sx[2], gr, gi, dr, di);
    apply_su2<2>(sr, si, gr, gi, dr, di);
    make_g2(M2, l * 4 + 3, cx[3], sx[3], gr, gi, dr, di);
    apply_su2<3>(sr, si, gr, gi, dr, di);
    apply_cnot_<2, 3>(sr, si);
    apply_cnot_<1, 2>(sr, si);
    apply_cnot_<0, 1>(sr, si);
    apply_cnot_<3, 0>(sr, si);
  }

  // ---- Measurement via butterfly tree ----
  v2f p[16];
#pragma unroll
  for (int k = 0; k < 16; ++k) p[k] = sr[k] * sr[k] + si[k] * si[k];
  v2f s2[8], d2[8];
#pragma unroll
  for (int k = 0; k < 8; ++k) { s2[k] = p[2 * k] + p[2 * k + 1]; d2[k] = p[2 * k] - p[2 * k + 1]; }
  v2f o3 = ((d2[0] + d2[1]) + (d2[2] + d2[3])) + ((d2[4] + d2[5]) + (d2[6] + d2[7]));
  v2f s4[4], d4[4];
#pragma unroll
  for (int k = 0; k < 4; ++k) { s4[k] = s2[2 * k] + s2[2 * k + 1]; d4[k] = s2[2 * k] - s2[2 * k + 1]; }
  v2f o2 = (d4[0] + d4[1]) + (d4[2] + d4[3]);
  v2f s8a = s4[0] + s4[1], s8b = s4[2] + s4[3];
  v2f d8a = s4[0] - s4[1], d8b = s4[2] - s4[3];
  v2f o1 = d8a + d8b;
  v2f o0 = s8a - s8b;

  float4* o4 = reinterpret_cast<float4*>(out);
  o4[2 * t]     = make_float4(o0.x, o1.x, o2.x, o3.x);
  o4[2 * t + 1] = make_float4(o0.y, o1.y, o2.y, o3.y);
}

extern "C" void kernel_launch(void* const* d_in, const int* in_sizes, int n_in,
                              void* d_out, int out_size, void* d_ws, size_t ws_size,
                              hipStream_t stream) {
  const float* x = (const float*)d_in[0];
  const float* w = (const float*)d_in[1];
  float* out = (float*)d_out;
  float* M = (float*)d_ws;   // 128 floats used (splatted)
  int nb = in_sizes[0] / 4;
  int np = nb / 2;           // 2 elements per thread; B=524288 -> np=262144

  hipLaunchKernelGGL(qlayer_precompute, dim3(1), dim3(64), 0, stream, w, M);
  int blocks = np / 256;     // exact: 1024 blocks
  hipLaunchKernelGGL(qlayer_main, dim3(blocks), dim3(256), 0, stream,
                     x, (const v2f*)M, out);
}

// Round 5
// 76.736 us; speedup vs baseline: 1.0180x; 1.0180x over previous
//
#include <hip/hip_runtime.h>

// QuantumLayer: 4-qubit, 4-layer VQC over batch B.
// R4 = R3 with the layer-0 in-place expansion sign bug fixed:
//   multiply by -conj(d) = (-dr, +di):  re = -dr*ar - di*ai,  im = di*ar - dr*ai.
// (256,3) launch bounds; two batch elements per thread in <2 x float> so all
// gate math lowers to v_pk_fma_f32.
// State indexing: flat k = w0*8 + w1*4 + w2*2 + w3  (wire i -> bit (3-i)).

typedef float v2f __attribute__((ext_vector_type(2)));

// ---- Precompute M = RZ(pz)*RY(py) per (layer, wire). SU(2): alpha=M00,
// beta=M01; each of {ar,ai,br,bi} written twice (splatted) at
// ws[(l*4+w)*8 + 2*j .. +1]. ----
__global__ void qlayer_precompute(const float* __restrict__ w, float* __restrict__ M) {
  int t = blockIdx.x * blockDim.x + threadIdx.x;
  if (t < 16) {
    int l = t >> 2, q = t & 3;
    float ay = 0.5f * w[8 * l + q];       // RY angle /2
    float az = 0.5f * w[8 * l + 4 + q];   // RZ angle /2
    float cy = cosf(ay), sy = sinf(ay);
    float cz = cosf(az), sz = sinf(az);
    float* m = M + t * 8;
    float ar = cz * cy, ai = -sz * cy, br = -cz * sy, bi = sz * sy;
    m[0] = ar; m[1] = ar;
    m[2] = ai; m[3] = ai;
    m[4] = br; m[5] = br;
    m[6] = bi; m[7] = bi;
  }
}

// G = M * RX(cx, sx) is SU(2): G = [[g, d], [-conj(d), conj(g)]].
// M2 entries are uniform v2f (splatted) -> SGPR pairs feeding VOP3P directly.
__device__ __forceinline__ void make_g2(const v2f* __restrict__ M2, int idx,
                                        v2f cx, v2f sxv,
                                        v2f& gr, v2f& gi, v2f& dr, v2f& di) {
  v2f ar = M2[idx * 4 + 0], ai = M2[idx * 4 + 1];
  v2f br = M2[idx * 4 + 2], bi = M2[idx * 4 + 3];
  gr = ar * cx + bi * sxv;
  gi = ai * cx - br * sxv;
  dr = ai * sxv + br * cx;
  di = bi * cx - ar * sxv;
}

// Apply SU(2) gate [[g,d],[-conj(d),conj(g)]] on wire W (bit 3-W).
template <int W>
__device__ __forceinline__ void apply_su2(v2f (&sr)[16], v2f (&si)[16],
                                          v2f gr, v2f gi, v2f dr, v2f di) {
  constexpr int stride = 8 >> W;
#pragma unroll
  for (int base = 0; base < 16; base += 2 * stride) {
#pragma unroll
    for (int j = 0; j < stride; ++j) {
      const int k0 = base + j, k1 = k0 + stride;
      v2f a0r = sr[k0], a0i = si[k0], a1r = sr[k1], a1i = si[k1];
      sr[k0] = gr * a0r - gi * a0i + dr * a1r - di * a1i;
      si[k0] = gr * a0i + gi * a0r + dr * a1i + di * a1r;
      sr[k1] = gr * a1r + gi * a1i - dr * a0r - di * a0i;
      si[k1] = gr * a1i - gi * a1r - dr * a0i + di * a0r;
    }
  }
}

// CNOT(control C, target T): pure register permutation (fully unrolled).
template <int C, int T>
__device__ __forceinline__ void apply_cnot_(v2f (&sr)[16], v2f (&si)[16]) {
  constexpr int cb = 8 >> C, tb = 8 >> T;
#pragma unroll
  for (int k = 0; k < 16; ++k) {
    if ((k & cb) && !(k & tb)) {
      const int k2 = k | tb;
      v2f tr = sr[k]; sr[k] = sr[k2]; sr[k2] = tr;
      v2f ti = si[k]; si[k] = si[k2]; si[k2] = ti;
    }
  }
}

__global__ __launch_bounds__(256, 3) void qlayer_main(const float* __restrict__ x,
                                                      const v2f* __restrict__ M2,
                                                      float* __restrict__ out) {
  int t = blockIdx.x * blockDim.x + threadIdx.x;  // owns batch elems 2t, 2t+1

  float4 xv0 = reinterpret_cast<const float4*>(x)[2 * t];
  float4 xv1 = reinterpret_cast<const float4*>(x)[2 * t + 1];
  v2f cx[4], sx[4];
  {
    float c, s;
    __sincosf(0.5f * xv0.x, &s, &c); sx[0].x = s; cx[0].x = c;
    __sincosf(0.5f * xv0.y, &s, &c); sx[1].x = s; cx[1].x = c;
    __sincosf(0.5f * xv0.z, &s, &c); sx[2].x = s; cx[2].x = c;
    __sincosf(0.5f * xv0.w, &s, &c); sx[3].x = s; cx[3].x = c;
    __sincosf(0.5f * xv1.x, &s, &c); sx[0].y = s; cx[0].y = c;
    __sincosf(0.5f * xv1.y, &s, &c); sx[1].y = s; cx[1].y = c;
    __sincosf(0.5f * xv1.z, &s, &c); sx[2].y = s; cx[2].y = c;
    __sincosf(0.5f * xv1.w, &s, &c); sx[3].y = s; cx[3].y = c;
  }

  v2f sr[16], si[16];

  // ---- Layer 0 on |0000>: product state, built IN-PLACE LSB-first.
  // Wire w column 0 of G_w is (g, -conj(d)).  bit=0 branch multiplies by
  // g=(gr,gi); bit=1 branch by -conj(d)=(-dr,+di):
  //   re = -dr*ar - di*ai,   im = di*ar - dr*ai. ----
  {
    v2f gr, gi, dr, di;
    // wire 3 (LSB): seed 2 amps
    make_g2(M2, 3, cx[3], sx[3], gr, gi, dr, di);
    sr[0] = gr;  si[0] = gi;
    sr[1] = -dr; si[1] = di;
    // wire 2: 2 -> 4
    make_g2(M2, 2, cx[2], sx[2], gr, gi, dr, di);
#pragma unroll
    for (int k = 1; k >= 0; --k) {
      v2f ar_ = sr[k], ai_ = si[k];
      sr[k + 2] = -(dr * ar_) - di * ai_;   // * (-conj(d)), real
      si[k + 2] = di * ar_ - dr * ai_;      // * (-conj(d)), imag
      sr[k]     = gr * ar_ - gi * ai_;      // * g
      si[k]     = gr * ai_ + gi * ar_;
    }
    // wire 1: 4 -> 8
    make_g2(M2, 1, cx[1], sx[1], gr, gi, dr, di);
#pragma unroll
    for (int k = 3; k >= 0; --k) {
      v2f ar_ = sr[k], ai_ = si[k];
      sr[k + 4] = -(dr * ar_) - di * ai_;
      si[k + 4] = di * ar_ - dr * ai_;
      sr[k]     = gr * ar_ - gi * ai_;
      si[k]     = gr * ai_ + gi * ar_;
    }
    // wire 0: 8 -> 16
    make_g2(M2, 0, cx[0], sx[0], gr, gi, dr, di);
#pragma unroll
    for (int k = 7; k >= 0; --k) {
      v2f ar_ = sr[k], ai_ = si[k];
      sr[k + 8] = -(dr * ar_) - di * ai_;
      si[k + 8] = di * ar_ - dr * ai_;
      sr[k]     = gr * ar_ - gi * ai_;
      si[k]     = gr * ai_ + gi * ar_;
    }
  }
  apply_cnot_<2, 3>(sr, si);
  apply_cnot_<1, 2>(sr, si);
  apply_cnot_<0, 1>(sr, si);
  apply_cnot_<3, 0>(sr, si);

  // ---- Layers 1..3 ----
#pragma unroll
  for (int l = 1; l < 4; ++l) {
    v2f gr, gi, dr, di;
    make_g2(M2, l * 4 + 0, cx[0], sx[0], gr, gi, dr, di);
    apply_su2<0>(sr, si, gr, gi, dr, di);
    make_g2(M2, l * 4 + 1, cx[1], sx[1], gr, gi, dr, di);
    apply_su2<1>(sr, si, gr, gi, dr, di);
    make_g2(M2, l * 4 + 2, cx[2], sx[2], gr, gi, dr, di);
    apply_su2<2>(sr, si, gr, gi, dr, di);
    make_g2(M2, l * 4 + 3, cx[3], sx[3], gr, gi, dr, di);
    apply_su2<3>(sr, si, gr, gi, dr, di);
    apply_cnot_<2, 3>(sr, si);
    apply_cnot_<1, 2>(sr, si);
    apply_cnot_<0, 1>(sr, si);
    apply_cnot_<3, 0>(sr, si);
  }

  // ---- Measurement via butterfly tree ----
  v2f p[16];
#pragma unroll
  for (int k = 0; k < 16; ++k) p[k] = sr[k] * sr[k] + si[k] * si[k];
  v2f s2[8], d2[8];
#pragma unroll
  for (int k = 0; k < 8; ++k) { s2[k] = p[2 * k] + p[2 * k + 1]; d2[k] = p[2 * k] - p[2 * k + 1]; }
  v2f o3 = ((d2[0] + d2[1]) + (d2[2] + d2[3])) + ((d2[4] + d2[5]) + (d2[6] + d2[7]));
  v2f s4[4], d4[4];
#pragma unroll
  for (int k = 0; k < 4; ++k) { s4[k] = s2[2 * k] + s2[2 * k + 1]; d4[k] = s2[2 * k] - s2[2 * k + 1]; }
  v2f o2 = (d4[0] + d4[1]) + (d4[2] + d4[3]);
  v2f s8a = s4[0] + s4[1], s8b = s4[2] + s4[3];
  v2f d8a = s4[0] - s4[1], d8b = s4[2] - s4[3];
  v2f o1 = d8a + d8b;
  v2f o0 = s8a - s8b;

  float4* o4 = reinterpret_cast<float4*>(out);
  o4[2 * t]     = make_float4(o0.x, o1.x, o2.x, o3.x);
  o4[2 * t + 1] = make_float4(o0.y, o1.y, o2.y, o3.y);
}

extern "C" void kernel_launch(void* const* d_in, const int* in_sizes, int n_in,
                              void* d_out, int out_size, void* d_ws, size_t ws_size,
                              hipStream_t stream) {
  const float* x = (const float*)d_in[0];
  const float* w = (const float*)d_in[1];
  float* out = (float*)d_out;
  float* M = (float*)d_ws;   // 128 floats used (splatted)
  int nb = in_sizes[0] / 4;
  int np = nb / 2;           // 2 elements per thread; B=524288 -> np=262144

  hipLaunchKernelGGL(qlayer_precompute, dim3(1), dim3(64), 0, stream, w, M);
  int blocks = np / 256;     // exact: 1024 blocks
  hipLaunchKernelGGL(qlayer_main, dim3(blocks), dim3(256), 0, stream,
                     x, (const v2f*)M, out);
}